// Round 4
// baseline (28815.262 us; speedup 1.0000x reference)
//
#include <hip/hip_runtime.h>
#include <hip/hip_cooperative_groups.h>
#include <math.h>

namespace cg = cooperative_groups;

#define VV 32000
#define EE 512
#define HH 512
#define BB 16
#define TT 128
#define SS 128
#define XD 1024
#define NPB 250
#define BH (BB*HH)

__device__ __forceinline__ float sigf(float x){ return 1.0f/(1.0f+expf(-x)); }

__device__ __forceinline__ float fget(const float4& v, int d){
    return d==0 ? v.x : d==1 ? v.y : d==2 ? v.z : v.w;
}

// lv layout: stride 20, stagger in {0,4} (fits the 4-float pad; no wrap, so
// rows can never alias: max(stagger)+15 = 19 < 20). float4-aligned.
__device__ __forceinline__ int lvoff(int row){ return row * 20 + (((row >> 2) & 1) << 2); }

// ---- block-wide reductions (512 threads = 8 waves), trailing sync so smem reusable ----
__device__ __forceinline__ float bredmax(float v, float* s8, int tid){
    #pragma unroll
    for (int o = 32; o >= 1; o >>= 1) v = fmaxf(v, __shfl_xor(v, o));
    if ((tid & 63) == 0) s8[tid >> 6] = v;
    __syncthreads();
    float r = fmaxf(fmaxf(fmaxf(s8[0],s8[1]),fmaxf(s8[2],s8[3])),
                    fmaxf(fmaxf(s8[4],s8[5]),fmaxf(s8[6],s8[7])));
    __syncthreads();
    return r;
}
__device__ __forceinline__ float bredsum(float v, float* s8, int tid){
    #pragma unroll
    for (int o = 32; o >= 1; o >>= 1) v += __shfl_xor(v, o);
    if ((tid & 63) == 0) s8[tid >> 6] = v;
    __syncthreads();
    float r = ((s8[0]+s8[1])+(s8[2]+s8[3]))+((s8[4]+s8[5])+(s8[6]+s8[7]));
    __syncthreads();
    return r;
}
__device__ __forceinline__ void bredamax(float& v, int& idx, float* s8, int* si8, int tid){
    #pragma unroll
    for (int o = 32; o >= 1; o >>= 1){
        float ov = __shfl_xor(v, o); int oi = __shfl_xor(idx, o);
        if (ov > v || (ov == v && oi < idx)) { v = ov; idx = oi; }
    }
    if ((tid & 63) == 0) { s8[tid >> 6] = v; si8[tid >> 6] = idx; }
    __syncthreads();
    float bv = s8[0]; int bi = si8[0];
    #pragma unroll
    for (int w = 1; w < 8; ++w){
        float ov = s8[w]; int oi = si8[w];
        if (ov > bv || (ov == bv && oi < bi)) { bv = ov; bi = oi; }
    }
    __syncthreads();
    v = bv; idx = bi;
}

// ---- one LSTM cell step: block owns 2 h-indices (8 gate rows), all 16 batches ----
template<int XLEN>
__device__ __forceinline__ void lstm_cell(
    int tid, int j0,
    const float* __restrict__ wih, const float* __restrict__ whh,
    const float* __restrict__ bih, const float* __restrict__ bhh,
    const float* __restrict__ xsrc,
    const float* __restrict__ hold, const float* __restrict__ cold,
    float* __restrict__ hnew, float* __restrict__ cnew)
{
    const int bb = tid >> 5, h32 = tid & 31;
    constexpr int KX = XLEN >> 5;   // 32 (layer0) or 16 (layer1)
    constexpr int KH = 16;          // 512/32
    float acc[8];
    #pragma unroll
    for (int r = 0; r < 8; ++r) acc[r] = 0.f;
    const float* xb = xsrc + bb * XLEN + h32 * KX;
    const float* hb = hold + (bb << 9) + h32 * KH;
    const float* wx[8]; const float* wh[8];
    #pragma unroll
    for (int r = 0; r < 8; ++r) {
        const int row = (r >> 1) * HH + j0 + (r & 1);   // gate=(r>>1), jj=(r&1)
        wx[r] = wih + (long)row * XLEN + h32 * KX;
        wh[r] = whh + ((long)row << 9) + h32 * KH;
    }
    #pragma unroll
    for (int i = 0; i < KX; i += 4) {
        float4 xv = *(const float4*)(xb + i);
        #pragma unroll
        for (int r = 0; r < 8; ++r) {
            float4 wv = *(const float4*)(wx[r] + i);
            acc[r] = fmaf(wv.w, xv.w, fmaf(wv.z, xv.z, fmaf(wv.y, xv.y, fmaf(wv.x, xv.x, acc[r]))));
        }
    }
    #pragma unroll
    for (int i = 0; i < KH; i += 4) {
        float4 xv = *(const float4*)(hb + i);
        #pragma unroll
        for (int r = 0; r < 8; ++r) {
            float4 wv = *(const float4*)(wh[r] + i);
            acc[r] = fmaf(wv.w, xv.w, fmaf(wv.z, xv.z, fmaf(wv.y, xv.y, fmaf(wv.x, xv.x, acc[r]))));
        }
    }
    #pragma unroll
    for (int o = 16; o >= 1; o >>= 1) {
        #pragma unroll
        for (int r = 0; r < 8; ++r) acc[r] += __shfl_xor(acc[r], o);
    }
    if (h32 == 0) {
        #pragma unroll
        for (int jj = 0; jj < 2; ++jj) {
            const int j = j0 + jj;
            const float gi = acc[0 + jj] + bih[j]          + bhh[j];
            const float gf = acc[2 + jj] + bih[HH + j]     + bhh[HH + j];
            const float gg = acc[4 + jj] + bih[2*HH + j]   + bhh[2*HH + j];
            const float go = acc[6 + jj] + bih[3*HH + j]   + bhh[3*HH + j];
            const float cp = cold[(bb << 9) + j];
            const float cn = sigf(gf) * cp + sigf(gi) * tanhf(gg);
            const float hn = sigf(go) * tanhf(cn);
            hnew[(bb << 9) + j] = hn;
            cnew[(bb << 9) + j] = cn;
        }
    }
}

// ---- attention scores for next step: scores[b,s] = dot(h1[b], enc[s,b,:]) ----
__device__ __forceinline__ void calc_scores(int blk, int tid,
    const float* __restrict__ h1, const float* __restrict__ enc, float* __restrict__ scores)
{
    const int idx = (blk - NPB) * 512 + tid;
    if (idx >= BB * SS) return;
    const int s = idx >> 4, b = idx & 15;
    const float* ep = enc + ((long)s * BB + b) * HH;
    const float* hp = h1 + b * HH;
    float a0 = 0.f, a1 = 0.f, a2 = 0.f, a3 = 0.f;
    #pragma unroll 2
    for (int k = 0; k < HH; k += 16) {
        float4 e0 = *(const float4*)(ep + k),      hv0 = *(const float4*)(hp + k);
        float4 e1 = *(const float4*)(ep + k + 4),  hv1 = *(const float4*)(hp + k + 4);
        float4 e2 = *(const float4*)(ep + k + 8),  hv2 = *(const float4*)(hp + k + 8);
        float4 e3 = *(const float4*)(ep + k + 12), hv3 = *(const float4*)(hp + k + 12);
        a0 += e0.x*hv0.x + e0.y*hv0.y + e0.z*hv0.z + e0.w*hv0.w;
        a1 += e1.x*hv1.x + e1.y*hv1.y + e1.z*hv1.z + e1.w*hv1.w;
        a2 += e2.x*hv2.x + e2.y*hv2.y + e2.z*hv2.z + e2.w*hv2.w;
        a3 += e3.x*hv3.x + e3.y*hv3.y + e3.z*hv3.z + e3.w*hv3.w;
    }
    scores[b * SS + s] = (a0 + a1) + (a2 + a3);
}

// ---- projection tile: 128 vocab rows/block, logits + softmax/argmax partials ----
__device__ __forceinline__ void proj_tile(
    int blk, int tid, const float* __restrict__ h1,
    const float* __restrict__ ow, const float* __restrict__ ob,
    float* __restrict__ rawt, long rstride,
    float* __restrict__ pm, float* __restrict__ psm, int* __restrict__ pid,
    float* __restrict__ h1t, float* __restrict__ lv)
{
    // stage h1 [k][b] staggered (stagger monotone in k -> collision-free)
    for (int i = tid; i < BB * HH; i += 512) {
        const int b = i >> 9, k = i & 511;
        h1t[k * 20 + ((k >> 5) << 2) + b] = h1[i];
    }
    __syncthreads();

    const int q = tid >> 4, h = tid & 15;   // q: 4-row group, h: k-sixteenth
    const int v0 = blk * 128 + q * 4;
    const int k0 = h << 5;
    float a[64];
    #pragma unroll
    for (int i = 0; i < 64; ++i) a[i] = 0.f;

    const float* w0 = ow + (long)v0 * HH + k0;
    #pragma unroll 2
    for (int kk = 0; kk < 32; kk += 4) {
        float4 wv0 = *(const float4*)(w0 + kk);
        float4 wv1 = *(const float4*)(w0 + HH + kk);
        float4 wv2 = *(const float4*)(w0 + 2 * HH + kk);
        float4 wv3 = *(const float4*)(w0 + 3 * HH + kk);
        #pragma unroll
        for (int d = 0; d < 4; ++d) {
            const int kd = k0 + kk + d;
            const float* hp = h1t + kd * 20 + ((kd >> 5) << 2);
            float4 hv0 = *(const float4*)(hp);
            float4 hv1 = *(const float4*)(hp + 4);
            float4 hv2 = *(const float4*)(hp + 8);
            float4 hv3 = *(const float4*)(hp + 12);
            const float hv[16] = {hv0.x,hv0.y,hv0.z,hv0.w, hv1.x,hv1.y,hv1.z,hv1.w,
                                  hv2.x,hv2.y,hv2.z,hv2.w, hv3.x,hv3.y,hv3.z,hv3.w};
            const float wr[4] = { fget(wv0,d), fget(wv1,d), fget(wv2,d), fget(wv3,d) };
            #pragma unroll
            for (int r = 0; r < 4; ++r)
                #pragma unroll
                for (int j = 0; j < 16; ++j)
                    a[r*16+j] = fmaf(wr[r], hv[j], a[r*16+j]);
        }
    }

    // reduce-scatter over the 16-lane k-group: 60 shuffles, each lane ends with 4 finals
#define RS_ROUND(O, NH)                                                  \
    {                                                                    \
        const bool up = (h & (O)) != 0;                                  \
        _Pragma("unroll")                                                \
        for (int i = 0; i < (NH); ++i) {                                 \
            float lo = a[i], hi = a[i + (NH)];                           \
            float snd = up ? lo : hi;                                    \
            float rcv = __shfl_xor(snd, (O));                            \
            a[i] = (up ? hi : lo) + rcv;                                 \
        }                                                                \
    }
    RS_ROUND(1, 32)
    RS_ROUND(2, 16)
    RS_ROUND(4, 8)
    RS_ROUND(8, 4)
#undef RS_ROUND
    // lane h holds global value indices g = 4*bitrev4(h) + {0..3}; g = r*16 + j
    const int br = ((h & 1) << 3) | ((h & 2) << 1) | ((h & 4) >> 1) | ((h & 8) >> 3);
    const int rr = br >> 2;
    const int jb = (br & 3) << 2;
    {
        const int row = q * 4 + rr;
        const float bv = ob[v0 + rr];
        float* dst = lv + lvoff(row) + jb;
        float4 val = { a[0] + bv, a[1] + bv, a[2] + bv, a[3] + bv };
        *(float4*)dst = val;
    }
    __syncthreads();

    // coalesced raw-logit store (plain store: read back next phase from L2)
    for (int i = tid; i < 128 * BB; i += 512) {
        const int b = i >> 7, row = i & 127;
        rawt[(long)b * rstride + blk * 128 + row] = lv[lvoff(row) + b];
    }

    // per-(block,b) partials: max / first-argmax / sum(exp(x-max))
    const int b2 = tid >> 5, l = tid & 31;
    float vals[4]; float m = -INFINITY; int mi = 0;
    #pragma unroll
    for (int r = 0; r < 4; ++r) {
        const int row = l * 4 + r;
        const float x = lv[lvoff(row) + b2];
        vals[r] = x;
        if (x > m) { m = x; mi = row; }
    }
    #pragma unroll
    for (int o = 16; o >= 1; o >>= 1) {
        float om = __shfl_xor(m, o); int oi = __shfl_xor(mi, o);
        if (om > m || (om == m && oi < mi)) { m = om; mi = oi; }
    }
    float z = 0.f;
    #pragma unroll
    for (int r = 0; r < 4; ++r) z += expf(vals[r] - m);
    #pragma unroll
    for (int o = 16; o >= 1; o >>= 1) z += __shfl_xor(z, o);
    if (l == 0) {
        pm[blk * BB + b2] = m;
        psm[blk * BB + b2] = z;
        pid[blk * BB + b2] = blk * 128 + mi;
    }
}

struct Params {
    const float *emb, *h0i, *c0i, *enc;
    const float *wih0, *whh0, *bih0, *bhh0;
    const float *wih1, *whh1, *bih1, *bhh1;
    const float *ow, *ob;
    float *out, *seqo, *attn;
    float *st, *xbuf, *scores, *pm, *psm;
    int *pid;
    float *lraw;
    int usews;
};

__global__ __launch_bounds__(512, 2) void k_decode(Params p)
{
    cg::grid_group grid = cg::this_grid();
    const int blk = blockIdx.x;
    const int tid = threadIdx.x;

    __shared__ float smem[12896];
    float* h1t = smem;            // proj phase: 10304
    float* lv  = smem + 10304;    // proj phase: 2560 (stride-20, stagger {0,4})
    float* aw  = smem;            // phase A alias: 128
    float* s8  = smem + 160;      // 8
    int*   si8 = (int*)(smem + 176);  // 8

    // prologue: scores for step 0 from initial top-layer hidden state
    if (blk >= NPB) calc_scores(blk, tid, p.h0i + BH, p.enc, p.scores);
    grid.sync();

    for (int t = 0; t <= TT; ++t) {
        // ---------------- phase A ----------------
        if (blk < BB) {
            const int b = blk;
            int tok = 1;
            if (t > 0) {
                float m = -INFINITY; int mi = 0x7fffffff;
                if (tid < NPB) { m = p.pm[tid * BB + b]; mi = p.pid[tid * BB + b]; }
                bredamax(m, mi, s8, si8, tid);
                tok = mi;
                if (tid == 0) p.seqo[b * TT + (t - 1)] = (float)tok;
            }
            if (t < TT) {
                float sc = (tid < SS) ? p.scores[b * SS + tid] : -INFINITY;
                float M = bredmax(sc, s8, tid);
                float e = (tid < SS) ? expf(sc - M) : 0.f;
                float Z = bredsum(e, s8, tid);
                float av = e / Z;
                if (tid < SS) {
                    aw[tid] = av;
                    __builtin_nontemporal_store(av, p.attn + ((long)b * TT + t) * SS + tid);
                }
                __syncthreads();
                float cacc = 0.f;
                const float* ep = p.enc + b * HH + tid;
                #pragma unroll 8
                for (int s = 0; s < SS; ++s)
                    cacc = fmaf(aw[s], ep[(long)s * BH], cacc);
                p.xbuf[b * XD + EE + tid] = cacc;
                p.xbuf[b * XD + tid] = p.emb[(long)tok * EE + tid];
            }
        } else if (t > 0) {
            // logp writers: 240 blocks, 15 per batch
            const int wb = blk - BB;
            const int b = wb / 15, c = wb - b * 15;
            float m = (tid < NPB) ? p.pm[tid * BB + b] : -INFINITY;
            m = bredmax(m, s8, tid);
            float z = (tid < NPB) ? p.psm[tid * BB + b] * expf(p.pm[tid * BB + b] - m) : 0.f;
            z = bredsum(z, s8, tid);
            const float lse = m + logf(z);
            const long obase = ((long)b * TT + (t - 1)) * (long)VV;
            const float* rb = p.usews ? (p.lraw + (long)b * VV) : (p.out + obase);
            float* obp = p.out + obase;
            const int v0 = c * 2134, v1 = min(v0 + 2134, VV);
            for (int v = v0 + tid; v < v1; v += 512)
                __builtin_nontemporal_store(__builtin_nontemporal_load(rb + v) - lse, obp + v);
        }
        if (t == TT) return;
        grid.sync();

        // state ping-pong
        const int po = t & 1, pn = (t + 1) & 1;
        const float* h0o = t ? p.st + (po * 4 + 0) * BH : p.h0i;
        const float* c0o = t ? p.st + (po * 4 + 1) * BH : p.c0i;
        const float* h1o = t ? p.st + (po * 4 + 2) * BH : p.h0i + BH;
        const float* c1o = t ? p.st + (po * 4 + 3) * BH : p.c0i + BH;
        float* h0n = p.st + (pn * 4 + 0) * BH;
        float* c0n = p.st + (pn * 4 + 1) * BH;
        float* h1n = p.st + (pn * 4 + 2) * BH;
        float* c1n = p.st + (pn * 4 + 3) * BH;

        // ---------------- phase B: LSTM layer 0 ----------------
        lstm_cell<XD>(tid, blk * 2, p.wih0, p.whh0, p.bih0, p.bhh0, p.xbuf, h0o, c0o, h0n, c0n);
        grid.sync();

        // ---------------- phase C: LSTM layer 1 ----------------
        lstm_cell<HH>(tid, blk * 2, p.wih1, p.whh1, p.bih1, p.bhh1, h0n, h1o, c1o, h1n, c1n);
        grid.sync();

        // ---------------- phase D: vocab projection + next scores ----------------
        {
            float* rawt = p.usews ? p.lraw : p.out + (long)t * VV;
            const long rstride = p.usews ? (long)VV : (long)TT * (long)VV;
            if (blk < NPB)
                proj_tile(blk, tid, h1n, p.ow, p.ob, rawt, rstride, p.pm, p.psm, p.pid, h1t, lv);
            else
                calc_scores(blk, tid, h1n, p.enc, p.scores);
        }
        grid.sync();
    }
}

extern "C" void kernel_launch(void* const* d_in, const int* in_sizes, int n_in,
                              void* d_out, int out_size, void* d_ws, size_t ws_size,
                              hipStream_t stream)
{
    (void)in_sizes; (void)n_in; (void)out_size;
    Params p;
    p.emb  = (const float*)d_in[0];
    p.h0i  = (const float*)d_in[1];
    p.c0i  = (const float*)d_in[2];
    p.enc  = (const float*)d_in[3];
    p.wih0 = (const float*)d_in[4];
    p.whh0 = (const float*)d_in[5];
    p.bih0 = (const float*)d_in[6];
    p.bhh0 = (const float*)d_in[7];
    p.wih1 = (const float*)d_in[8];
    p.whh1 = (const float*)d_in[9];
    p.bih1 = (const float*)d_in[10];
    p.bhh1 = (const float*)d_in[11];
    p.ow   = (const float*)d_in[12];
    p.ob   = (const float*)d_in[13];

    float* out = (float*)d_out;
    p.out  = out;
    p.seqo = out + (long)BB * TT * VV;
    p.attn = p.seqo + (long)BB * TT;

    float* ws = (float*)d_ws;
    p.st     = ws;                       // 2 x {h0,c0,h1,c1} x B*H
    p.xbuf   = p.st + 8 * BH;            // B x XD
    p.scores = p.xbuf + BB * XD;         // B x S
    p.pm     = p.scores + BB * SS;       // NPB x B
    p.psm    = p.pm + NPB * BB;
    p.pid    = (int*)(p.psm + NPB * BB);
    p.lraw   = (float*)(p.pid + NPB * BB);   // B x V
    const size_t need = (size_t)((char*)(p.lraw + (long)BB * VV) - (char*)ws);
    p.usews = (ws_size >= need) ? 1 : 0;

    void* args[] = { &p };
    hipLaunchCooperativeKernel((void*)k_decode, dim3(256), dim3(512), args, 0, stream);
}

// Round 7
// 27889.023 us; speedup vs baseline: 1.0332x; 1.0332x over previous
//
#include <hip/hip_runtime.h>
#include <hip/hip_cooperative_groups.h>
#include <math.h>

namespace cg = cooperative_groups;

#define VV 32000
#define EE 512
#define HH 512
#define BB 16
#define TT 128
#define SS 128
#define XD 1024
#define NB 256
#define NT 512
#define BH (BB*HH)
#define RPB 125          // vocab rows per block (256*125 = 32000)
#define W0STR 1728       // 1536 + max stagger 188, monotone-safe
#define W1STR 1152       // 1024 + max stagger 124

// ---- LDS layout (floats) ----
#define OFF_W0  0                       // 8 rows x 1728 = 13824
#define OFF_W1  13824                   // 8 rows x 1152 = 9216
#define OFF_H   23040                   // h1 stage 8256; phase-A/B scratch aliases here
#define OFF_LV  31296                   // logits tile 128*20 = 2560
#define OFF_OB  33856                   // out_b slice (128)
#define OFF_BS  33984                   // lstm bias sums (16)
#define OFF_CST 34000                   // c-state [layer][jj*16+b] (64)
#define SMEMF   34064                   // 136,256 B <= 160 KB

// phase-A scratch (aliases OFF_H region; dead during phase D)
#define A_HB   (OFF_H)                  // 512
#define A_SC   (OFF_H+512)              // 128
#define A_AW   (OFF_H+640)              // 128
#define A_S8   (OFF_H+768)              // 8
#define A_SI8  (OFF_H+776)              // 8 (ints)
#define A_LSE  (OFF_H+784)              // 16
#define A_GP   (OFF_H+1024)             // lstm gate partials 8*32 = 256

__device__ __forceinline__ float sigf(float x){ return 1.0f/(1.0f+expf(-x)); }
__device__ __forceinline__ float fget(const float4& v, int d){
    return d==0 ? v.x : d==1 ? v.y : d==2 ? v.z : v.w;
}
__device__ __forceinline__ int lvoff(int row){ return row*20 + (((row>>2)&1)<<2); }
__device__ __forceinline__ float dot4f(float4 w, float4 x, float acc){
    return fmaf(w.w,x.w, fmaf(w.z,x.z, fmaf(w.y,x.y, fmaf(w.x,x.x, acc))));
}
// MONOTONE stagger: offset strictly increasing in k (step 1 or 5) -> collision-free
__device__ __forceinline__ int stg(int k){ return k + 4*(k>>5); }
// staggered LDS fetch of a float4 at virtual offset vk within a weight row
__device__ __forceinline__ float4 wat(const float* wb, int vk){
    return *(const float4*)(wb + stg(vk));
}

// ---- block-wide reductions (512 thr), trailing sync so scratch reusable ----
__device__ __forceinline__ float bredmax(float v, float* s8, int tid){
    #pragma unroll
    for (int o = 32; o >= 1; o >>= 1) v = fmaxf(v, __shfl_xor(v, o));
    if ((tid & 63) == 0) s8[tid >> 6] = v;
    __syncthreads();
    float r = fmaxf(fmaxf(fmaxf(s8[0],s8[1]),fmaxf(s8[2],s8[3])),
                    fmaxf(fmaxf(s8[4],s8[5]),fmaxf(s8[6],s8[7])));
    __syncthreads();
    return r;
}
__device__ __forceinline__ float bredsum(float v, float* s8, int tid){
    #pragma unroll
    for (int o = 32; o >= 1; o >>= 1) v += __shfl_xor(v, o);
    if ((tid & 63) == 0) s8[tid >> 6] = v;
    __syncthreads();
    float r = ((s8[0]+s8[1])+(s8[2]+s8[3]))+((s8[4]+s8[5])+(s8[6]+s8[7]));
    __syncthreads();
    return r;
}
__device__ __forceinline__ void bredamax(float& v, int& idx, float* s8, int* si8, int tid){
    #pragma unroll
    for (int o = 32; o >= 1; o >>= 1){
        float ov = __shfl_xor(v, o); int oi = __shfl_xor(idx, o);
        if (ov > v || (ov == v && oi < idx)) { v = ov; idx = oi; }
    }
    if ((tid & 63) == 0) { s8[tid >> 6] = v; si8[tid >> 6] = idx; }
    __syncthreads();
    float bv = s8[0]; int bi = si8[0];
    #pragma unroll
    for (int w = 1; w < 8; ++w){
        float ov = s8[w]; int oi = si8[w];
        if (ov > bv || (ov == bv && oi < bi)) { bv = ov; bi = oi; }
    }
    __syncthreads();
    v = bv; idx = bi;
}

// reduce-scatter rounds (R4-verified pattern)
#define RS_ROUND_L(LN, O, NH)                                            \
    {                                                                    \
        const bool up = ((LN) & (O)) != 0;                               \
        _Pragma("unroll")                                                \
        for (int i = 0; i < (NH); ++i) {                                 \
            float lo = a[i], hi = a[i + (NH)];                           \
            float snd = up ? lo : hi;                                    \
            float rcv = __shfl_xor(snd, (O));                            \
            a[i] = (up ? hi : lo) + rcv;                                 \
        }                                                                \
    }

struct Params {
    const float *emb, *h0i, *c0i, *enc;
    const float *wih0, *whh0, *bih0, *bhh0;
    const float *wih1, *whh1, *bih1, *bhh1;
    const float *ow, *ob;
    float *out, *seqo, *attn;
    float *st, *xbuf, *pm, *psm, *lse_ws;
    int *pid;
};

__global__ __launch_bounds__(512, 2) void k_decode(Params p)
{
    cg::grid_group grid = cg::this_grid();
    __shared__ float smem[SMEMF];
    const int blk = blockIdx.x;
    const int tid = threadIdx.x;
    const int gv0 = blk * RPB;
    const int j0  = blk * 2;
    float* s8  = smem + A_S8;
    int*   si8 = (int*)(smem + A_SI8);

    // ================= prologue (once) =================
    // LSTM0 weights -> LDS (virtual k: [0,1024)=wih0 row, [1024,1536)=whh0 row)
    #pragma unroll
    for (int r = 0; r < 8; ++r) {
        const int row = (r >> 1) * HH + j0 + (r & 1);
        for (int k = tid; k < 1536; k += NT) {
            const float v = (k < 1024) ? p.wih0[(long)row*1024 + k]
                                       : p.whh0[(long)row*512 + (k-1024)];
            smem[OFF_W0 + r*W0STR + stg(k)] = v;
        }
    }
    // LSTM1 weights -> LDS (virtual k: [0,512)=wih1, [512,1024)=whh1)
    #pragma unroll
    for (int r = 0; r < 8; ++r) {
        const int row = (r >> 1) * HH + j0 + (r & 1);
        for (int k = tid; k < 1024; k += NT) {
            const float v = (k < 512) ? p.wih1[(long)row*512 + k]
                                      : p.whh1[(long)row*512 + (k-512)];
            smem[OFF_W1 + r*W1STR + stg(k)] = v;
        }
    }
    if (tid < 8) {
        const int row = (tid >> 1) * HH + j0 + (tid & 1);
        smem[OFF_BS + tid]     = p.bih0[row] + p.bhh0[row];
        smem[OFF_BS + 8 + tid] = p.bih1[row] + p.bhh1[row];
    }
    if (tid < 32) {      // c-state init [layer][jj*16+b]
        const int jj = tid & 1, b = tid >> 1;
        smem[OFF_CST + jj*16 + b]      = p.c0i[b*HH + j0 + jj];
        smem[OFF_CST + 32 + jj*16 + b] = p.c0i[BH + b*HH + j0 + jj];
    }
    for (int i = tid; i < 128; i += NT)
        smem[OFF_OB + i] = p.ob[gv0 + min(i, RPB-1)];

    // out_w -> VGPRs: thread (q,h): rows {q, 32+q, 64+q, min(96+q,124)}, k-slice h*32..+32
    const int q = tid >> 4, h = tid & 15;
    float4 w4[32];
    {
        const float4* ow4 = (const float4*)p.ow;
        #pragma unroll
        for (int r = 0; r < 4; ++r) {
            const int row = (r < 3) ? (q + r*32) : min(96 + q, RPB-1);
            const long rb = (long)(gv0 + row) * 128 + h * 8;
            #pragma unroll
            for (int c = 0; c < 8; ++c) w4[r*8 + c] = ow4[rb + c];
        }
    }
    __syncthreads();

    for (int t = 0; t <= TT; ++t) {
        // ================= phase A (blocks 0..15, b = blk) =================
        if (blk < BB) {
            const int b = blk;
            int tok = 1;
            if (t > 0) {
                float pmv = -INFINITY, psv = 0.f; int mi = 0x7fffffff;
                if (tid < NB) { pmv = p.pm[tid*BB+b]; psv = p.psm[tid*BB+b]; mi = p.pid[tid*BB+b]; }
                float M = pmv; int Mi = mi;
                bredamax(M, Mi, s8, si8, tid);
                tok = Mi;
                float z = (tid < NB) ? psv * expf(pmv - M) : 0.f;
                z = bredsum(z, s8, tid);
                if (tid == 0) {
                    p.seqo[b*TT + (t-1)] = (float)tok;
                    p.lse_ws[b] = M + logf(z);
                }
            }
            if (t < TT) {
                const float* h1cur = t ? (p.st + ((t&1)*4 + 2)*BH) : (p.h0i + BH);
                smem[A_HB + tid] = h1cur[b*HH + tid];
                __syncthreads();
                {   // scores[s] = dot(h1[b], enc[s][b]); 4 lanes per s
                    const int s = tid >> 2, kq = tid & 3;
                    const float* ep = p.enc + ((long)s*BB + b)*HH + kq*128;
                    const float* hp = smem + A_HB + kq*128;
                    float a0=0,a1=0,a2=0,a3=0;
                    #pragma unroll 4
                    for (int k = 0; k < 128; k += 16) {
                        float4 e0 = *(const float4*)(ep+k),    v0 = *(const float4*)(hp+k);
                        float4 e1 = *(const float4*)(ep+k+4),  v1 = *(const float4*)(hp+k+4);
                        float4 e2 = *(const float4*)(ep+k+8),  v2 = *(const float4*)(hp+k+8);
                        float4 e3 = *(const float4*)(ep+k+12), v3 = *(const float4*)(hp+k+12);
                        a0 += e0.x*v0.x+e0.y*v0.y+e0.z*v0.z+e0.w*v0.w;
                        a1 += e1.x*v1.x+e1.y*v1.y+e1.z*v1.z+e1.w*v1.w;
                        a2 += e2.x*v2.x+e2.y*v2.y+e2.z*v2.z+e2.w*v2.w;
                        a3 += e3.x*v3.x+e3.y*v3.y+e3.z*v3.z+e3.w*v3.w;
                    }
                    float a = (a0+a1)+(a2+a3);
                    a += __shfl_xor(a, 1); a += __shfl_xor(a, 2);
                    if (kq == 0) smem[A_SC + s] = a;
                }
                __syncthreads();
                float sc = (tid < SS) ? smem[A_SC + tid] : -INFINITY;
                float M2 = bredmax(sc, s8, tid);
                float e  = (tid < SS) ? expf(sc - M2) : 0.f;
                float Z2 = bredsum(e, s8, tid);
                if (tid < SS) {
                    const float av = e / Z2;
                    smem[A_AW + tid] = av;
                    __builtin_nontemporal_store(av, p.attn + ((long)b*TT + t)*SS + tid);
                }
                __syncthreads();
                float c0=0,c1=0,c2=0,c3=0;
                const float* ep2 = p.enc + b*HH + tid;
                for (int s = 0; s < SS; s += 4) {
                    c0 = fmaf(smem[A_AW+s],   ep2[(long)s*BH],     c0);
                    c1 = fmaf(smem[A_AW+s+1], ep2[(long)(s+1)*BH], c1);
                    c2 = fmaf(smem[A_AW+s+2], ep2[(long)(s+2)*BH], c2);
                    c3 = fmaf(smem[A_AW+s+3], ep2[(long)(s+3)*BH], c3);
                }
                p.xbuf[b*XD + EE + tid] = (c0+c1)+(c2+c3);
                p.xbuf[b*XD + tid] = p.emb[(long)tok*EE + tid];
            }
        }
        grid.sync();

        // ================= phase B: lse stage + LSTM0 + logp write (t-1) =====
        if (t > 0) {
            if (tid < BB) smem[A_LSE + tid] = p.lse_ws[tid];
            __syncthreads();
        }
        if (t < TT) {
            const float* xsrc = p.xbuf;
            const float* hold = t ? p.st + ((t&1)*4 + 0)*BH : p.h0i;
            float* hnew = p.st + (((t+1)&1)*4 + 0)*BH;

            const int g4 = tid >> 7, l = tid & 127, lane = tid & 63, wh = (tid >> 6) & 1;
            const float* wbA = smem + OFF_W0 + (g4*2)   * W0STR;
            const float* wbB = smem + OFF_W0 + (g4*2+1) * W0STR;
            const float4 wxaA = wat(wbA, 8*l), wxbA = wat(wbA, 8*l+4), whA = wat(wbA, 1024+4*l);
            const float4 wxaB = wat(wbB, 8*l), wxbB = wat(wbB, 8*l+4), whB = wat(wbB, 1024+4*l);
            float a[32];
            #pragma unroll
            for (int b = 0; b < 16; ++b) {
                const float4 xa = *(const float4*)(xsrc + b*XD + 8*l);
                const float4 xb = *(const float4*)(xsrc + b*XD + 8*l + 4);
                const float4 hv = *(const float4*)(hold + b*HH + 4*l);
                a[b]      = dot4f(whA, hv, dot4f(wxbA, xb, dot4f(wxaA, xa, 0.f)));
                a[16 + b] = dot4f(whB, hv, dot4f(wxbB, xb, dot4f(wxaB, xa, 0.f)));
            }
            RS_ROUND_L(lane, 1, 16) RS_ROUND_L(lane, 2, 8)
            RS_ROUND_L(lane, 4, 4)  RS_ROUND_L(lane, 8, 2)
            RS_ROUND_L(lane, 16, 1)
            float v = a[0]; v += __shfl_xor(v, 32);
            const int lg = lane & 31;
            const int g = ((lg&1)<<4)|((lg&2)<<2)|(lg&4)|((lg&8)>>2)|((lg&16)>>4);
            if (lane < 32) smem[A_GP + (g4*2 + wh)*32 + g] = v;
            __syncthreads();
            if (tid < 32) {
                const int b = tid >> 1, jj = tid & 1, gg2 = jj*16 + b;
                const float gi = smem[A_GP + 0*32+gg2] + smem[A_GP + 1*32+gg2] + smem[OFF_BS + 0 + jj];
                const float gf = smem[A_GP + 2*32+gg2] + smem[A_GP + 3*32+gg2] + smem[OFF_BS + 2 + jj];
                const float gc = smem[A_GP + 4*32+gg2] + smem[A_GP + 5*32+gg2] + smem[OFF_BS + 4 + jj];
                const float go = smem[A_GP + 6*32+gg2] + smem[A_GP + 7*32+gg2] + smem[OFF_BS + 6 + jj];
                const float cp = smem[OFF_CST + jj*16 + b];
                const float cn = sigf(gf)*cp + sigf(gi)*tanhf(gc);
                const float hn = sigf(go)*tanhf(cn);
                smem[OFF_CST + jj*16 + b] = cn;
                hnew[b*HH + j0 + jj] = hn;
            }
        }
        if (t > 0) {
            for (int i = tid; i < BB*128; i += NT) {
                const int b2 = i >> 7, r = i & 127;
                if (r < RPB)
                    __builtin_nontemporal_store(smem[OFF_LV + lvoff(r) + b2] - smem[A_LSE + b2],
                                                p.out + ((long)b2*TT + (t-1))*VV + gv0 + r);
            }
        }
        if (t == TT) break;
        grid.sync();

        // ================= phase C: LSTM1 =================
        {
            const float* xsrc = p.st + (((t+1)&1)*4 + 0)*BH;   // h0 new
            const float* hold = t ? p.st + ((t&1)*4 + 2)*BH : p.h0i + BH;
            float* hnew = p.st + (((t+1)&1)*4 + 2)*BH;

            const int g4 = tid >> 7, l = tid & 127, lane = tid & 63, wh = (tid >> 6) & 1;
            const float* wbA = smem + OFF_W1 + (g4*2)   * W1STR;
            const float* wbB = smem + OFF_W1 + (g4*2+1) * W1STR;
            const float4 wxA = wat(wbA, 4*l), whA = wat(wbA, 512+4*l);
            const float4 wxB = wat(wbB, 4*l), whB = wat(wbB, 512+4*l);
            float a[32];
            #pragma unroll
            for (int b = 0; b < 16; ++b) {
                const float4 xa = *(const float4*)(xsrc + b*HH + 4*l);
                const float4 hv = *(const float4*)(hold + b*HH + 4*l);
                a[b]      = dot4f(whA, hv, dot4f(wxA, xa, 0.f));
                a[16 + b] = dot4f(whB, hv, dot4f(wxB, xa, 0.f));
            }
            RS_ROUND_L(lane, 1, 16) RS_ROUND_L(lane, 2, 8)
            RS_ROUND_L(lane, 4, 4)  RS_ROUND_L(lane, 8, 2)
            RS_ROUND_L(lane, 16, 1)
            float v = a[0]; v += __shfl_xor(v, 32);
            const int lg = lane & 31;
            const int g = ((lg&1)<<4)|((lg&2)<<2)|(lg&4)|((lg&8)>>2)|((lg&16)>>4);
            if (lane < 32) smem[A_GP + (g4*2 + wh)*32 + g] = v;
            __syncthreads();
            if (tid < 32) {
                const int b = tid >> 1, jj = tid & 1, gg2 = jj*16 + b;
                const float gi = smem[A_GP + 0*32+gg2] + smem[A_GP + 1*32+gg2] + smem[OFF_BS + 8 + 0 + jj];
                const float gf = smem[A_GP + 2*32+gg2] + smem[A_GP + 3*32+gg2] + smem[OFF_BS + 8 + 2 + jj];
                const float gc = smem[A_GP + 4*32+gg2] + smem[A_GP + 5*32+gg2] + smem[OFF_BS + 8 + 4 + jj];
                const float go = smem[A_GP + 6*32+gg2] + smem[A_GP + 7*32+gg2] + smem[OFF_BS + 8 + 6 + jj];
                const float cp = smem[OFF_CST + 32 + jj*16 + b];
                const float cn = sigf(gf)*cp + sigf(gi)*tanhf(gc);
                const float hn = sigf(go)*tanhf(cn);
                smem[OFF_CST + 32 + jj*16 + b] = cn;
                hnew[b*HH + j0 + jj] = hn;
            }
        }
        grid.sync();

        // ================= phase D: vocab projection =================
        {
            const float* h1n = p.st + (((t+1)&1)*4 + 2)*BH;
            // h1 stage [kd][b]: offset kd*16 + 4*(kd>>5) strictly increasing
            // with step >= 16 -> 16-wide b-blocks never overlap
            for (int i = tid; i < BH; i += NT) {
                const int b = i >> 9, kd = i & 511;
                smem[OFF_H + kd*16 + 4*(kd>>5) + b] = h1n[b*HH + kd];
            }
            __syncthreads();

            float a[64];
            #pragma unroll
            for (int i = 0; i < 64; ++i) a[i] = 0.f;

            // lane's kd = h*32 + cc -> kd>>5 == h -> stagger 4*h
            const float* hb0 = smem + OFF_H + (h << 5)*16 + 4*h;
            #pragma unroll
            for (int c = 0; c < 8; ++c) {
                #pragma unroll
                for (int d = 0; d < 4; ++d) {
                    const float* hp = hb0 + ((c<<2) + d)*16;
                    float4 hv0 = *(const float4*)(hp);
                    float4 hv1 = *(const float4*)(hp + 4);
                    float4 hv2 = *(const float4*)(hp + 8);
                    float4 hv3 = *(const float4*)(hp + 12);
                    const float hv[16] = {hv0.x,hv0.y,hv0.z,hv0.w, hv1.x,hv1.y,hv1.z,hv1.w,
                                          hv2.x,hv2.y,hv2.z,hv2.w, hv3.x,hv3.y,hv3.z,hv3.w};
                    const float wr[4] = { fget(w4[c],d), fget(w4[8+c],d),
                                          fget(w4[16+c],d), fget(w4[24+c],d) };
                    #pragma unroll
                    for (int r = 0; r < 4; ++r)
                        #pragma unroll
                        for (int j = 0; j < 16; ++j)
                            a[r*16+j] = fmaf(wr[r], hv[j], a[r*16+j]);
                }
            }
            // reduce-scatter over 16-lane k-group (R4-verified)
            RS_ROUND_L(h, 1, 32) RS_ROUND_L(h, 2, 16)
            RS_ROUND_L(h, 4, 8)  RS_ROUND_L(h, 8, 4)
            {
                const int br = ((h&1)<<3) | ((h&2)<<1) | ((h&4)>>1) | ((h&8)>>3);
                const int rr = br >> 2;
                const int jb = (br & 3) << 2;
                const int row = rr*32 + q;
                const float bv = smem[OFF_OB + row];
                float4 val = { a[0]+bv, a[1]+bv, a[2]+bv, a[3]+bv };
                *(float4*)&smem[OFF_LV + lvoff(row) + jb] = val;
            }
            __syncthreads();

            // per-(block,b) partials: max / first-argmax / sum(exp(x-max))
            const int b2 = tid >> 5, l = tid & 31;
            float vals[4]; float m = -INFINITY; int mi = 0x7fffffff;
            #pragma unroll
            for (int r = 0; r < 4; ++r) {
                const int row = l*4 + r;
                const float x = (row < RPB) ? smem[OFF_LV + lvoff(row) + b2] : -INFINITY;
                vals[r] = x;
                if (x > m) { m = x; mi = row; }
            }
            #pragma unroll
            for (int o = 16; o >= 1; o >>= 1) {
                float om = __shfl_xor(m, o); int oi = __shfl_xor(mi, o);
                if (om > m || (om == m && oi < mi)) { m = om; mi = oi; }
            }
            float z = 0.f;
            #pragma unroll
            for (int r = 0; r < 4; ++r) z += expf(vals[r] - m);
            #pragma unroll
            for (int o = 16; o >= 1; o >>= 1) z += __shfl_xor(z, o);
            if (l == 0) {
                p.pm[blk*BB + b2]  = m;
                p.psm[blk*BB + b2] = z;
                p.pid[blk*BB + b2] = gv0 + mi;
            }
        }
        grid.sync();
    }
}

extern "C" void kernel_launch(void* const* d_in, const int* in_sizes, int n_in,
                              void* d_out, int out_size, void* d_ws, size_t ws_size,
                              hipStream_t stream)
{
    (void)in_sizes; (void)n_in; (void)out_size; (void)ws_size;
    Params p;
    p.emb  = (const float*)d_in[0];
    p.h0i  = (const float*)d_in[1];
    p.c0i  = (const float*)d_in[2];
    p.enc  = (const float*)d_in[3];
    p.wih0 = (const float*)d_in[4];
    p.whh0 = (const float*)d_in[5];
    p.bih0 = (const float*)d_in[6];
    p.bhh0 = (const float*)d_in[7];
    p.wih1 = (const float*)d_in[8];
    p.whh1 = (const float*)d_in[9];
    p.bih1 = (const float*)d_in[10];
    p.bhh1 = (const float*)d_in[11];
    p.ow   = (const float*)d_in[12];
    p.ob   = (const float*)d_in[13];

    float* out = (float*)d_out;
    p.out  = out;
    p.seqo = out + (long)BB*TT*VV;
    p.attn = p.seqo + (long)BB*TT;

    float* ws = (float*)d_ws;
    p.st     = ws;                       // 2 x {h0,c0,h1,c1} x B*H (c slots unused)
    p.xbuf   = p.st + 8*BH;              // B x XD
    p.pm     = p.xbuf + BB*XD;           // NB x B
    p.psm    = p.pm + NB*BB;
    p.pid    = (int*)(p.psm + NB*BB);
    p.lse_ws = (float*)(p.pid + NB*BB);  // 16

    void* args[] = { &p };
    hipLaunchCooperativeKernel((void*)k_decode, dim3(NB), dim3(NT), args, 0, stream);
}

// Round 8
// 26213.483 us; speedup vs baseline: 1.0993x; 1.0639x over previous
//
#include <hip/hip_runtime.h>
#include <math.h>

#define VV 32000
#define EE 512
#define HH 512
#define BB 16
#define TT 128
#define SS 128
#define NB 256
#define NT 512
#define BH (BB*HH)
#define RPB 125          // vocab rows per block (256*125 = 32000)
#define W0STR 1728       // 1536 + max monotone stagger, collision-free
#define W1STR 1152       // 1024 + max monotone stagger

// ---- LDS layout (floats) ----
#define OFF_W0  0                       // 8 x 1728 = 13824
#define OFF_W1  13824                   // 8 x 1152 = 9216
#define OFF_H   23040                   // proj h1 stage 8256 (P phase only)
#define OFF_LV  31296                   // logits tile 128*20 = 2560 (P->B, block-local)
#define OFF_OB  33856                   // out_b slice (128)
#define OFF_BS  33984                   // lstm bias sums (16)
#define OFF_CST 34000                   // c-state [layer][jj*16+b] (64)
#define OFF_TOK 34064                   // 16 ints
#define OFF_LSEL 34080                  // 16 floats
#define OFF_S8  34096                   // 8
#define OFF_SI8 34104                   // 8 (ints)
#define OFF_ATT 34112                   // 768: attn scratch (P); A_GP alias (B/C)
#define A_HB   (OFF_ATT)                // 512
#define A_SC   (OFF_ATT+512)            // 128
#define A_AW   (OFF_ATT+640)            // 128
#define A_GP   (OFF_ATT)                // gate partials 256 (B/C phases)
#define SMEMF  34880                    // 139,520 B <= 160 KB

__device__ __forceinline__ float sigf(float x){ return 1.0f/(1.0f+expf(-x)); }
__device__ __forceinline__ float fget(const float4& v, int d){
    return d==0 ? v.x : d==1 ? v.y : d==2 ? v.z : v.w;
}
__device__ __forceinline__ int lvoff(int row){ return row*20 + (((row>>2)&1)<<2); }
// MONOTONE stagger (R7-verified): strictly increasing -> collision-free
__device__ __forceinline__ int stg(int k){ return k + 4*(k>>5); }
__device__ __forceinline__ float4 wat(const float* wb, int vk){
    return *(const float4*)(wb + stg(vk));
}

// ---- LLC-routed (agent/coherent-point) data ops for cross-block state ----
__device__ __forceinline__ float aload(const float* p){
    return __hip_atomic_load(const_cast<float*>(p), __ATOMIC_RELAXED, __HIP_MEMORY_SCOPE_AGENT);
}
__device__ __forceinline__ int aloadi(const int* p){
    return __hip_atomic_load(const_cast<int*>(p), __ATOMIC_RELAXED, __HIP_MEMORY_SCOPE_AGENT);
}
__device__ __forceinline__ void astore(float* p, float v){
    __hip_atomic_store(p, v, __ATOMIC_RELAXED, __HIP_MEMORY_SCOPE_AGENT);
}
__device__ __forceinline__ void astorei(int* p, int v){
    __hip_atomic_store(p, v, __ATOMIC_RELAXED, __HIP_MEMORY_SCOPE_AGENT);
}

// ---- fence-free tree barrier ----
// Safe because: (a) __syncthreads() drains vmcnt on every wave, so ALL the
// block's astores are complete at the coherent point before thread 0 arrives;
// (b) every cross-block datum is written astore / read aload (LLC), so no
// cache invalidation is needed; immutable data keeps plain cached loads.
__device__ __forceinline__ void gbar(int* wsb, int tgt){
    __syncthreads();
    if (threadIdx.x == 0){
        int* leaf = wsb + (blockIdx.x & 15)*32;
        int* root = wsb + 512;
        int* gen  = wsb + 576;
        int old = __hip_atomic_fetch_add(leaf, 1, __ATOMIC_RELAXED, __HIP_MEMORY_SCOPE_AGENT);
        if (old == tgt*16 - 1){
            int ro = __hip_atomic_fetch_add(root, 1, __ATOMIC_RELAXED, __HIP_MEMORY_SCOPE_AGENT);
            if (ro == tgt*16 - 1)
                __hip_atomic_store(gen, tgt, __ATOMIC_RELAXED, __HIP_MEMORY_SCOPE_AGENT);
        }
        while (__hip_atomic_load(gen, __ATOMIC_RELAXED, __HIP_MEMORY_SCOPE_AGENT) < tgt)
            __builtin_amdgcn_s_sleep(2);
    }
    __syncthreads();
}

// ---- block reductions on 512 threads (attn softmax) ----
__device__ __forceinline__ float bredmax(float v, float* s8, int tid){
    #pragma unroll
    for (int o = 32; o >= 1; o >>= 1) v = fmaxf(v, __shfl_xor(v, o));
    if ((tid & 63) == 0) s8[tid >> 6] = v;
    __syncthreads();
    float r = fmaxf(fmaxf(fmaxf(s8[0],s8[1]),fmaxf(s8[2],s8[3])),
                    fmaxf(fmaxf(s8[4],s8[5]),fmaxf(s8[6],s8[7])));
    __syncthreads();
    return r;
}
__device__ __forceinline__ float bredsum(float v, float* s8, int tid){
    #pragma unroll
    for (int o = 32; o >= 1; o >>= 1) v += __shfl_xor(v, o);
    if ((tid & 63) == 0) s8[tid >> 6] = v;
    __syncthreads();
    float r = ((s8[0]+s8[1])+(s8[2]+s8[3]))+((s8[4]+s8[5])+(s8[6]+s8[7]));
    __syncthreads();
    return r;
}

#define RS_ROUND_L(LN, O, NH)                                            \
    {                                                                    \
        const bool up = ((LN) & (O)) != 0;                               \
        _Pragma("unroll")                                                \
        for (int i2 = 0; i2 < (NH); ++i2) {                              \
            float lo = a[i2], hi = a[i2 + (NH)];                         \
            float snd = up ? lo : hi;                                    \
            float rcv = __shfl_xor(snd, (O));                            \
            a[i2] = (up ? hi : lo) + rcv;                                \
        }                                                                \
    }

struct Params {
    const float *emb, *h0i, *c0i, *enc;
    const float *wih0, *whh0, *bih0, *bhh0;
    const float *wih1, *whh1, *bih1, *bhh1;
    const float *ow, *ob;
    float *out, *seqo, *attn;
    int *wsbar;
    float *st, *xbuf, *pm, *psm;
    int *pid;
};

__global__ __launch_bounds__(512, 2) void k_decode(Params p)
{
    __shared__ float smem[SMEMF];
    const int blk = blockIdx.x;
    const int tid = threadIdx.x;
    const int gv0 = blk * RPB;
    const int j0  = blk * 2;
    float* s8  = smem + OFF_S8;
    int bt = 0;

    // ================= prologue (once) =================
    #pragma unroll
    for (int r = 0; r < 8; ++r) {
        const int row = (r >> 1) * HH + j0 + (r & 1);
        for (int k = tid; k < 1536; k += NT) {
            const float v = (k < 1024) ? p.wih0[(long)row*1024 + k]
                                       : p.whh0[(long)row*512 + (k-1024)];
            smem[OFF_W0 + r*W0STR + stg(k)] = v;
        }
    }
    #pragma unroll
    for (int r = 0; r < 8; ++r) {
        const int row = (r >> 1) * HH + j0 + (r & 1);
        for (int k = tid; k < 1024; k += NT) {
            const float v = (k < 512) ? p.wih1[(long)row*512 + k]
                                      : p.whh1[(long)row*512 + (k-512)];
            smem[OFF_W1 + r*W1STR + stg(k)] = v;
        }
    }
    if (tid < 8) {
        const int row = (tid >> 1) * HH + j0 + (tid & 1);
        smem[OFF_BS + tid]     = p.bih0[row] + p.bhh0[row];
        smem[OFF_BS + 8 + tid] = p.bih1[row] + p.bhh1[row];
    }
    if (tid < 32) {
        const int jj = tid & 1, b = tid >> 1;
        smem[OFF_CST + jj*16 + b]      = p.c0i[b*HH + j0 + jj];
        smem[OFF_CST + 32 + jj*16 + b] = p.c0i[BH + b*HH + j0 + jj];
    }
    for (int i = tid; i < 128; i += NT)
        smem[OFF_OB + i] = p.ob[gv0 + min(i, RPB-1)];

    const int q = tid >> 4, h = tid & 15;
    float4 w4[32];
    {
        const float4* ow4 = (const float4*)p.ow;
        #pragma unroll
        for (int r = 0; r < 4; ++r) {
            const int row = (r < 3) ? (q + r*32) : min(96 + q, RPB-1);
            const long rb = (long)(gv0 + row) * 128 + h * 8;
            #pragma unroll
            for (int c = 0; c < 8; ++c) w4[r*8 + c] = ow4[rb + c];
        }
    }
    __syncthreads();

    for (int i = 0; i <= TT; ++i) {
        const int pp = (i-1) & 1;   // parity of h[i-1] (i>=1)
        const int pc = i & 1;       // parity of h[i]

        // ================= phase P: proj(h1[i-1]) + attn->ctx[i] =============
        if (i >= 1) {
            const float* h1p = p.st + (pp*2 + 1)*BH;
            for (int ii = tid; ii < BH; ii += NT) {
                const int b = ii >> 9, kd = ii & 511;
                smem[OFF_H + kd*16 + 4*(kd>>5) + b] = aload(h1p + b*HH + kd);
            }
            __syncthreads();

            float a[64];
            #pragma unroll
            for (int ii = 0; ii < 64; ++ii) a[ii] = 0.f;
            const float* hb0 = smem + OFF_H + (h << 5)*16 + 4*h;
            #pragma unroll
            for (int c = 0; c < 8; ++c) {
                #pragma unroll
                for (int d = 0; d < 4; ++d) {
                    const float* hp = hb0 + ((c<<2) + d)*16;
                    float4 hv0 = *(const float4*)(hp);
                    float4 hv1 = *(const float4*)(hp + 4);
                    float4 hv2 = *(const float4*)(hp + 8);
                    float4 hv3 = *(const float4*)(hp + 12);
                    const float hv[16] = {hv0.x,hv0.y,hv0.z,hv0.w, hv1.x,hv1.y,hv1.z,hv1.w,
                                          hv2.x,hv2.y,hv2.z,hv2.w, hv3.x,hv3.y,hv3.z,hv3.w};
                    const float wr[4] = { fget(w4[c],d), fget(w4[8+c],d),
                                          fget(w4[16+c],d), fget(w4[24+c],d) };
                    #pragma unroll
                    for (int r = 0; r < 4; ++r)
                        #pragma unroll
                        for (int j = 0; j < 16; ++j)
                            a[r*16+j] = fmaf(wr[r], hv[j], a[r*16+j]);
                }
            }
            RS_ROUND_L(h, 1, 32) RS_ROUND_L(h, 2, 16)
            RS_ROUND_L(h, 4, 8)  RS_ROUND_L(h, 8, 4)
            {
                const int br = ((h&1)<<3) | ((h&2)<<1) | ((h&4)>>1) | ((h&8)>>3);
                const int rr = br >> 2;
                const int jb = (br & 3) << 2;
                const int row = rr*32 + q;
                const float bv = smem[OFF_OB + row];
                float4 val = { a[0]+bv, a[1]+bv, a[2]+bv, a[3]+bv };
                *(float4*)&smem[OFF_LV + lvoff(row) + jb] = val;
            }
            __syncthreads();

            const int b2 = tid >> 5, l = tid & 31;
            float vals[4]; float m = -INFINITY; int mi = 0x7fffffff;
            #pragma unroll
            for (int r = 0; r < 4; ++r) {
                const int row = l*4 + r;
                const float x = (row < RPB) ? smem[OFF_LV + lvoff(row) + b2] : -INFINITY;
                vals[r] = x;
                if (x > m) { m = x; mi = row; }
            }
            #pragma unroll
            for (int o = 16; o >= 1; o >>= 1) {
                float om = __shfl_xor(m, o); int oi = __shfl_xor(mi, o);
                if (om > m || (om == m && oi < mi)) { m = om; mi = oi; }
            }
            float z = 0.f;
            #pragma unroll
            for (int r = 0; r < 4; ++r) z += expf(vals[r] - m);
            #pragma unroll
            for (int o = 16; o >= 1; o >>= 1) z += __shfl_xor(z, o);
            if (l == 0) {
                astore(p.pm  + blk*BB + b2, m);
                astore(p.psm + blk*BB + b2, z);
                astorei(p.pid + blk*BB + b2, gv0 + mi);
            }
        }
        if (blk < BB && i < TT) {
            const int b = blk;
            if (i == 0) smem[A_HB + tid] = p.h0i[BH + b*HH + tid];
            else        smem[A_HB + tid] = smem[OFF_H + tid*16 + 4*(tid>>5) + b];
            __syncthreads();
            {   // scores[s] = dot(h1prev[b], enc[s][b]); 4 lanes per s
                const int s = tid >> 2, kq = tid & 3;
                const float* ep = p.enc + ((long)s*BB + b)*HH + kq*128;
                const float* hp = smem + A_HB + kq*128;
                float a0=0,a1=0,a2=0,a3=0;
                #pragma unroll 4
                for (int k = 0; k < 128; k += 16) {
                    float4 e0 = *(const float4*)(ep+k),    v0 = *(const float4*)(hp+k);
                    float4 e1 = *(const float4*)(ep+k+4),  v1 = *(const float4*)(hp+k+4);
                    float4 e2 = *(const float4*)(ep+k+8),  v2 = *(const float4*)(hp+k+8);
                    float4 e3 = *(const float4*)(ep+k+12), v3 = *(const float4*)(hp+k+12);
                    a0 += e0.x*v0.x+e0.y*v0.y+e0.z*v0.z+e0.w*v0.w;
                    a1 += e1.x*v1.x+e1.y*v1.y+e1.z*v1.z+e1.w*v1.w;
                    a2 += e2.x*v2.x+e2.y*v2.y+e2.z*v2.z+e2.w*v2.w;
                    a3 += e3.x*v3.x+e3.y*v3.y+e3.z*v3.z+e3.w*v3.w;
                }
                float a = (a0+a1)+(a2+a3);
                a += __shfl_xor(a, 1); a += __shfl_xor(a, 2);
                if (kq == 0) smem[A_SC + s] = a;
            }
            __syncthreads();
            float sc = (tid < SS) ? smem[A_SC + tid] : -INFINITY;
            float M2 = bredmax(sc, s8, tid);
            float e  = (tid < SS) ? expf(sc - M2) : 0.f;
            float Z2 = bredsum(e, s8, tid);
            if (tid < SS) {
                const float av = e / Z2;
                smem[A_AW + tid] = av;
                __builtin_nontemporal_store(av, p.attn + ((long)b*TT + i)*SS + tid);
            }
            __syncthreads();
            float c0=0,c1=0,c2=0,c3=0;
            const float* ep2 = p.enc + b*HH + tid;
            for (int s = 0; s < SS; s += 4) {
                c0 = fmaf(smem[A_AW+s],   ep2[(long)s*BH],     c0);
                c1 = fmaf(smem[A_AW+s+1], ep2[(long)(s+1)*BH], c1);
                c2 = fmaf(smem[A_AW+s+2], ep2[(long)(s+2)*BH], c2);
                c3 = fmaf(smem[A_AW+s+3], ep2[(long)(s+3)*BH], c3);
            }
            astore(p.xbuf + b*HH + tid, (c0+c1)+(c2+c3));
        }
        gbar(p.wsbar, ++bt);

        // ================= phase B: combine + logp(i-1) + LSTM0 ==============
        if (i >= 1) {
            const int bC = tid >> 5, lC = tid & 31;
            float pmv[8]; float psv[8]; int piv[8];
            #pragma unroll
            for (int j2 = 0; j2 < 8; ++j2) {
                const int src = (lC + 32*j2)*BB + bC;
                pmv[j2] = aload(p.pm + src);
                psv[j2] = aload(p.psm + src);
                piv[j2] = aloadi(p.pid + src);
            }
            float M = pmv[0]; int Mi = piv[0];
            #pragma unroll
            for (int j2 = 1; j2 < 8; ++j2)
                if (pmv[j2] > M || (pmv[j2] == M && piv[j2] < Mi)) { M = pmv[j2]; Mi = piv[j2]; }
            #pragma unroll
            for (int o = 16; o >= 1; o >>= 1) {
                float om = __shfl_xor(M, o); int oi = __shfl_xor(Mi, o);
                if (om > M || (om == M && oi < Mi)) { M = om; Mi = oi; }
            }
            float z = 0.f;
            #pragma unroll
            for (int j2 = 0; j2 < 8; ++j2) z += psv[j2] * expf(pmv[j2] - M);
            #pragma unroll
            for (int o = 16; o >= 1; o >>= 1) z += __shfl_xor(z, o);
            if (lC == 0) {
                ((int*)smem)[OFF_TOK + bC] = Mi;
                smem[OFF_LSEL + bC] = M + logf(z);
            }
        } else {
            if (tid < BB) ((int*)smem)[OFF_TOK + tid] = 1;
        }
        __syncthreads();

        if (i >= 1) {
            if (blk < BB && tid == 0)
                __builtin_nontemporal_store((float)((int*)smem)[OFF_TOK + blk],
                                            p.seqo + blk*TT + (i-1));
            for (int ii = tid; ii < BB*128; ii += NT) {
                const int b2 = ii >> 7, r = ii & 127;
                if (r < RPB)
                    __builtin_nontemporal_store(smem[OFF_LV + lvoff(r) + b2] - smem[OFF_LSEL + b2],
                                                p.out + ((long)b2*TT + (i-1))*VV + gv0 + r);
            }
        }
        if (i < TT) {
            const float* hold = (i == 0) ? p.h0i : p.st + (pp*2)*BH;
            float* hnew = p.st + (pc*2)*BH;
            const int g4 = tid >> 7, l = tid & 127, lane = tid & 63, wh2 = (tid >> 6) & 1;
            const float* wbA = smem + OFF_W0 + (g4*2)   * W0STR;
            const float* wbB = smem + OFF_W0 + (g4*2+1) * W0STR;
            const float4 wxaA = wat(wbA, 8*l), wxbA = wat(wbA, 8*l+4), whA = wat(wbA, 1024+4*l);
            const float4 wxaB = wat(wbB, 8*l), wxbB = wat(wbB, 8*l+4), whB = wat(wbB, 1024+4*l);
            int toks[16];
            #pragma unroll
            for (int b = 0; b < 16; ++b) toks[b] = ((int*)smem)[OFF_TOK + b];
            float a[32];
            #pragma unroll
            for (int b = 0; b < 16; ++b) {
                float x0,x1,x2,x3,x4,x5,x6,x7;
                if (l < 64) {
                    const float4 e0 = *(const float4*)(p.emb + (long)toks[b]*EE + 8*l);
                    const float4 e1 = *(const float4*)(p.emb + (long)toks[b]*EE + 8*l + 4);
                    x0=e0.x; x1=e0.y; x2=e0.z; x3=e0.w;
                    x4=e1.x; x5=e1.y; x6=e1.z; x7=e1.w;
                } else {
                    const float* cb = p.xbuf + b*HH + (8*l - 512);
                    x0=aload(cb);   x1=aload(cb+1); x2=aload(cb+2); x3=aload(cb+3);
                    x4=aload(cb+4); x5=aload(cb+5); x6=aload(cb+6); x7=aload(cb+7);
                }
                const float* hb2 = hold + b*HH + 4*l;
                const float h0v=aload(hb2), h1v=aload(hb2+1), h2v=aload(hb2+2), h3v=aload(hb2+3);
                float sA = 0.f, sB = 0.f;
                sA = fmaf(wxaA.x,x0, fmaf(wxaA.y,x1, fmaf(wxaA.z,x2, fmaf(wxaA.w,x3, sA))));
                sA = fmaf(wxbA.x,x4, fmaf(wxbA.y,x5, fmaf(wxbA.z,x6, fmaf(wxbA.w,x7, sA))));
                sA = fmaf(whA.x,h0v, fmaf(whA.y,h1v, fmaf(whA.z,h2v, fmaf(whA.w,h3v, sA))));
                sB = fmaf(wxaB.x,x0, fmaf(wxaB.y,x1, fmaf(wxaB.z,x2, fmaf(wxaB.w,x3, sB))));
                sB = fmaf(wxbB.x,x4, fmaf(wxbB.y,x5, fmaf(wxbB.z,x6, fmaf(wxbB.w,x7, sB))));
                sB = fmaf(whB.x,h0v, fmaf(whB.y,h1v, fmaf(whB.z,h2v, fmaf(whB.w,h3v, sB))));
                a[b] = sA; a[16 + b] = sB;
            }
            RS_ROUND_L(lane, 1, 16) RS_ROUND_L(lane, 2, 8)
            RS_ROUND_L(lane, 4, 4)  RS_ROUND_L(lane, 8, 2)
            RS_ROUND_L(lane, 16, 1)
            float v = a[0]; v += __shfl_xor(v, 32);
            const int lg = lane & 31;
            const int g = ((lg&1)<<4)|((lg&2)<<2)|(lg&4)|((lg&8)>>2)|((lg&16)>>4);
            if (lane < 32) smem[A_GP + (g4*2 + wh2)*32 + g] = v;
            __syncthreads();
            if (tid < 32) {
                const int b = tid >> 1, jj = tid & 1, gg2 = jj*16 + b;
                const float gi = smem[A_GP + 0*32+gg2] + smem[A_GP + 1*32+gg2] + smem[OFF_BS + 0 + jj];
                const float gf = smem[A_GP + 2*32+gg2] + smem[A_GP + 3*32+gg2] + smem[OFF_BS + 2 + jj];
                const float gc = smem[A_GP + 4*32+gg2] + smem[A_GP + 5*32+gg2] + smem[OFF_BS + 4 + jj];
                const float go = smem[A_GP + 6*32+gg2] + smem[A_GP + 7*32+gg2] + smem[OFF_BS + 6 + jj];
                const float cp = smem[OFF_CST + jj*16 + b];
                const float cn = sigf(gf)*cp + sigf(gi)*tanhf(gc);
                const float hn = sigf(go)*tanhf(cn);
                smem[OFF_CST + jj*16 + b] = cn;
                astore(hnew + b*HH + j0 + jj, hn);
            }
        }
        if (i == TT) break;
        gbar(p.wsbar, ++bt);

        // ================= phase C: LSTM1 =================
        {
            const float* xsrc = p.st + (pc*2)*BH;                       // h0[i]
            const float* hold = (i == 0) ? p.h0i + BH : p.st + (pp*2 + 1)*BH;
            float* hnew = p.st + (pc*2 + 1)*BH;
            const int g4 = tid >> 7, l = tid & 127, lane = tid & 63, wh2 = (tid >> 6) & 1;
            const float* wbA = smem + OFF_W1 + (g4*2)   * W1STR;
            const float* wbB = smem + OFF_W1 + (g4*2+1) * W1STR;
            const float4 wxA = wat(wbA, 4*l), whA = wat(wbA, 512+4*l);
            const float4 wxB = wat(wbB, 4*l), whB = wat(wbB, 512+4*l);
            float a[32];
            #pragma unroll
            for (int b = 0; b < 16; ++b) {
                const float* xb2 = xsrc + b*HH + 4*l;
                const float* hb2 = hold + b*HH + 4*l;
                const float x0=aload(xb2), x1=aload(xb2+1), x2=aload(xb2+2), x3=aload(xb2+3);
                const float h0v=aload(hb2), h1v=aload(hb2+1), h2v=aload(hb2+2), h3v=aload(hb2+3);
                float sA = 0.f, sB = 0.f;
                sA = fmaf(wxA.x,x0, fmaf(wxA.y,x1, fmaf(wxA.z,x2, fmaf(wxA.w,x3, sA))));
                sA = fmaf(whA.x,h0v, fmaf(whA.y,h1v, fmaf(whA.z,h2v, fmaf(whA.w,h3v, sA))));
                sB = fmaf(wxB.x,x0, fmaf(wxB.y,x1, fmaf(wxB.z,x2, fmaf(wxB.w,x3, sB))));
                sB = fmaf(whB.x,h0v, fmaf(whB.y,h1v, fmaf(whB.z,h2v, fmaf(whB.w,h3v, sB))));
                a[b] = sA; a[16 + b] = sB;
            }
            RS_ROUND_L(lane, 1, 16) RS_ROUND_L(lane, 2, 8)
            RS_ROUND_L(lane, 4, 4)  RS_ROUND_L(lane, 8, 2)
            RS_ROUND_L(lane, 16, 1)
            float v = a[0]; v += __shfl_xor(v, 32);
            const int lg = lane & 31;
            const int g = ((lg&1)<<4)|((lg&2)<<2)|(lg&4)|((lg&8)>>2)|((lg&16)>>4);
            if (lane < 32) smem[A_GP + (g4*2 + wh2)*32 + g] = v;
            __syncthreads();
            if (tid < 32) {
                const int b = tid >> 1, jj = tid & 1, gg2 = jj*16 + b;
                const float gi = smem[A_GP + 0*32+gg2] + smem[A_GP + 1*32+gg2] + smem[OFF_BS + 8 + 0 + jj];
                const float gf = smem[A_GP + 2*32+gg2] + smem[A_GP + 3*32+gg2] + smem[OFF_BS + 8 + 2 + jj];
                const float gc = smem[A_GP + 4*32+gg2] + smem[A_GP + 5*32+gg2] + smem[OFF_BS + 8 + 4 + jj];
                const float go = smem[A_GP + 6*32+gg2] + smem[A_GP + 7*32+gg2] + smem[OFF_BS + 8 + 6 + jj];
                const float cp = smem[OFF_CST + 32 + jj*16 + b];
                const float cn = sigf(gf)*cp + sigf(gi)*tanhf(gc);
                const float hn = sigf(go)*tanhf(cn);
                smem[OFF_CST + 32 + jj*16 + b] = cn;
                astore(hnew + b*HH + j0 + jj, hn);
            }
        }
        gbar(p.wsbar, ++bt);
    }
}

extern "C" void kernel_launch(void* const* d_in, const int* in_sizes, int n_in,
                              void* d_out, int out_size, void* d_ws, size_t ws_size,
                              hipStream_t stream)
{
    (void)in_sizes; (void)n_in; (void)out_size; (void)ws_size;
    Params p;
    p.emb  = (const float*)d_in[0];
    p.h0i  = (const float*)d_in[1];
    p.c0i  = (const float*)d_in[2];
    p.enc  = (const float*)d_in[3];
    p.wih0 = (const float*)d_in[4];
    p.whh0 = (const float*)d_in[5];
    p.bih0 = (const float*)d_in[6];
    p.bhh0 = (const float*)d_in[7];
    p.wih1 = (const float*)d_in[8];
    p.whh1 = (const float*)d_in[9];
    p.bih1 = (const float*)d_in[10];
    p.bhh1 = (const float*)d_in[11];
    p.ow   = (const float*)d_in[12];
    p.ob   = (const float*)d_in[13];

    float* out = (float*)d_out;
    p.out  = out;
    p.seqo = out + (long)BB*TT*VV;
    p.attn = p.seqo + (long)BB*TT;

    p.wsbar = (int*)d_ws;                      // 1024 ints (4 KB), zeroed below
    float* base = (float*)d_ws + 1024;
    p.st    = base;                            // 2 parity x {h0,h1} x B*H = 32768
    p.xbuf  = p.st + 4*BH;                     // ctx: B x H = 8192
    p.pm    = p.xbuf + BH;                     // NB x B = 4096
    p.psm   = p.pm + NB*BB;                    // 4096
    p.pid   = (int*)(p.psm + NB*BB);           // 4096

    hipMemsetAsync(d_ws, 0, 4096, stream);     // reset barrier state every launch
    void* args[] = { &p };
    hipLaunchCooperativeKernel((void*)k_decode, dim3(NB), dim3(NT), args, 0, stream);
}

// Round 10
// 20955.058 us; speedup vs baseline: 1.3751x; 1.2509x over previous
//
#include <hip/hip_runtime.h>
#include <math.h>

#define VV 32000
#define EE 512
#define HH 512
#define BB 16
#define TT 128
#define SS 128
#define NB 256
#define NT 512
#define BH (BB*HH)
#define RPB 125          // vocab rows per block (256*125 = 32000)
#define W0STR 1728       // 1536 + max monotone stagger, collision-free
#define W1STR 1152       // 1024 + max monotone stagger

// ---- LDS layout (floats) ----
#define OFF_W0  0                       // 8 x 1728 = 13824
#define OFF_W1  13824                   // 8 x 1152 = 9216 -> 23040
#define OFF_H   23040                   // proj h1 stage 8704 (max 511*16+508+15=8699)
#define OFF_LV  31744                   // logits tile 128*20 = 2560
#define OFF_OB  34304                   // out_b slice (128)
#define OFF_BS  34432                   // lstm bias sums (16)
#define OFF_CST 34448                   // c-state [layer][jj*16+b] (64)
#define OFF_TOK 34512                   // 16 ints
#define OFF_LSEL 34528                  // 16 floats
#define OFF_S8  34544                   // 8
#define OFF_SI8 34552                   // 8 (ints)
#define OFF_ATT 34560                   // 768: attn scratch (P); A_GP alias (B/C)
#define A_HB   (OFF_ATT)                // 512
#define A_SC   (OFF_ATT+512)            // 128
#define A_AW   (OFF_ATT+640)            // 128
#define A_GP   (OFF_ATT)                // gate partials 256 (B/C phases)
#define SMEMF  35328                    // 141,312 B <= 160 KB

__device__ __forceinline__ float sigf(float x){ return 1.0f/(1.0f+expf(-x)); }
__device__ __forceinline__ float fget(const float4& v, int d){
    return d==0 ? v.x : d==1 ? v.y : d==2 ? v.z : v.w;
}
__device__ __forceinline__ int lvoff(int row){ return row*20 + (((row>>2)&1)<<2); }
// MONOTONE stagger (R7-verified): strictly increasing -> collision-free
__device__ __forceinline__ int stg(int k){ return k + 4*(k>>5); }
__device__ __forceinline__ float4 wat(const float* wb, int vk){
    return *(const float4*)(wb + stg(vk));
}
// h1 stage: kd*16 + 4*(kd>>2). UNMASKED monotone pad (no &7 wrap -- R9's bug):
// base step is +16 or +20, never negative => 16-wide b-blocks never overlap.
// Bank: lane h reads kd=4h+64c+d -> base mod 32 = 4h mod 32 -> 2-way (free).
__device__ __forceinline__ int hoff(int kd){ return kd*16 + 4*(kd>>2); }

// ---- LLC-routed (agent/coherent-point) data ops for cross-block state ----
__device__ __forceinline__ float aload(const float* p){
    return __hip_atomic_load(const_cast<float*>(p), __ATOMIC_RELAXED, __HIP_MEMORY_SCOPE_AGENT);
}
__device__ __forceinline__ int aloadi(const int* p){
    return __hip_atomic_load(const_cast<int*>(p), __ATOMIC_RELAXED, __HIP_MEMORY_SCOPE_AGENT);
}
__device__ __forceinline__ void astore(float* p, float v){
    __hip_atomic_store(p, v, __ATOMIC_RELAXED, __HIP_MEMORY_SCOPE_AGENT);
}
__device__ __forceinline__ void astorei(int* p, int v){
    __hip_atomic_store(p, v, __ATOMIC_RELAXED, __HIP_MEMORY_SCOPE_AGENT);
}

// ---- fence-free tree barrier (R8-verified correct & fast) ----
__device__ __forceinline__ void gbar(int* wsb, int tgt){
    __syncthreads();
    if (threadIdx.x == 0){
        int* leaf = wsb + (blockIdx.x & 15)*32;
        int* root = wsb + 512;
        int* gen  = wsb + 576;
        int old = __hip_atomic_fetch_add(leaf, 1, __ATOMIC_RELAXED, __HIP_MEMORY_SCOPE_AGENT);
        if (old == tgt*16 - 1){
            int ro = __hip_atomic_fetch_add(root, 1, __ATOMIC_RELAXED, __HIP_MEMORY_SCOPE_AGENT);
            if (ro == tgt*16 - 1)
                __hip_atomic_store(gen, tgt, __ATOMIC_RELAXED, __HIP_MEMORY_SCOPE_AGENT);
        }
        while (__hip_atomic_load(gen, __ATOMIC_RELAXED, __HIP_MEMORY_SCOPE_AGENT) < tgt)
            __builtin_amdgcn_s_sleep(2);
    }
    __syncthreads();
}

// ---- block reductions on 512 threads (attn softmax) ----
__device__ __forceinline__ float bredmax(float v, float* s8, int tid){
    #pragma unroll
    for (int o = 32; o >= 1; o >>= 1) v = fmaxf(v, __shfl_xor(v, o));
    if ((tid & 63) == 0) s8[tid >> 6] = v;
    __syncthreads();
    float r = fmaxf(fmaxf(fmaxf(s8[0],s8[1]),fmaxf(s8[2],s8[3])),
                    fmaxf(fmaxf(s8[4],s8[5]),fmaxf(s8[6],s8[7])));
    __syncthreads();
    return r;
}
__device__ __forceinline__ float bredsum(float v, float* s8, int tid){
    #pragma unroll
    for (int o = 32; o >= 1; o >>= 1) v += __shfl_xor(v, o);
    if ((tid & 63) == 0) s8[tid >> 6] = v;
    __syncthreads();
    float r = ((s8[0]+s8[1])+(s8[2]+s8[3]))+((s8[4]+s8[5])+(s8[6]+s8[7]));
    __syncthreads();
    return r;
}

#define RS_ROUND_L(LN, O, NH)                                            \
    {                                                                    \
        const bool up = ((LN) & (O)) != 0;                               \
        _Pragma("unroll")                                                \
        for (int i2 = 0; i2 < (NH); ++i2) {                              \
            float lo = a[i2], hi = a[i2 + (NH)];                         \
            float snd = up ? lo : hi;                                    \
            float rcv = __shfl_xor(snd, (O));                            \
            a[i2] = (up ? hi : lo) + rcv;                                \
        }                                                                \
    }

struct Params {
    const float *emb, *h0i, *c0i, *enc;
    const float *wih0, *whh0, *bih0, *bhh0;
    const float *wih1, *whh1, *bih1, *bhh1;
    const float *ow, *ob;
    float *out, *seqo, *attn;
    int *wsbar;
    float *st, *xbuf, *pm, *psm;
    int *pid;
};

__global__ __launch_bounds__(512, 2) void k_decode(Params p)
{
    __shared__ float smem[SMEMF];
    const int blk = blockIdx.x;
    const int tid = threadIdx.x;
    const int gv0 = blk * RPB;
    const int j0  = blk * 2;
    float* s8  = smem + OFF_S8;
    int bt = 0;

    // ================= prologue (once) =================
    #pragma unroll
    for (int r = 0; r < 8; ++r) {
        const int row = (r >> 1) * HH + j0 + (r & 1);
        for (int k = tid; k < 1536; k += NT) {
            const float v = (k < 1024) ? p.wih0[(long)row*1024 + k]
                                       : p.whh0[(long)row*512 + (k-1024)];
            smem[OFF_W0 + r*W0STR + stg(k)] = v;
        }
    }
    #pragma unroll
    for (int r = 0; r < 8; ++r) {
        const int row = (r >> 1) * HH + j0 + (r & 1);
        for (int k = tid; k < 1024; k += NT) {
            const float v = (k < 512) ? p.wih1[(long)row*512 + k]
                                      : p.whh1[(long)row*512 + (k-512)];
            smem[OFF_W1 + r*W1STR + stg(k)] = v;
        }
    }
    if (tid < 8) {
        const int row = (tid >> 1) * HH + j0 + (tid & 1);
        smem[OFF_BS + tid]     = p.bih0[row] + p.bhh0[row];
        smem[OFF_BS + 8 + tid] = p.bih1[row] + p.bhh1[row];
    }
    if (tid < 32) {
        const int jj = tid & 1, b = tid >> 1;
        smem[OFF_CST + jj*16 + b]      = p.c0i[b*HH + j0 + jj];
        smem[OFF_CST + 32 + jj*16 + b] = p.c0i[BH + b*HH + j0 + jj];
    }
    for (int i = tid; i < 128; i += NT)
        smem[OFF_OB + i] = p.ob[gv0 + min(i, RPB-1)];

    const int q = tid >> 4, h = tid & 15;
    // global row bases for this thread's 4 proj rows (k-strips 4h + 64c)
    const float* wr0 = p.ow + (long)(gv0 + q)*HH + 4*h;
    const float* wr1 = p.ow + (long)(gv0 + 32 + q)*HH + 4*h;
    const float* wr2 = p.ow + (long)(gv0 + 64 + q)*HH + 4*h;
    const float* wr3 = p.ow + (long)(gv0 + min(96 + q, RPB-1))*HH + 4*h;
    __syncthreads();

    for (int i = 0; i <= TT; ++i) {
        const int pp = (i-1) & 1;   // parity of h[i-1] (i>=1)
        const int pc = i & 1;       // parity of h[i]

        // ================= phase P: proj(h1[i-1]) + attn->ctx[i] =============
        if (i >= 1) {
            const float* h1p = p.st + (pp*2 + 1)*BH;
            for (int ii = tid; ii < BH; ii += NT) {
                const int b = ii >> 9, kd = ii & 511;
                smem[OFF_H + hoff(kd) + b] = aload(h1p + b*HH + kd);
            }
            __syncthreads();

            float a[64];
            #pragma unroll
            for (int ii = 0; ii < 64; ++ii) a[ii] = 0.f;
            #pragma unroll
            for (int c = 0; c < 8; ++c) {
                // coalesced: wave's 16 h-lanes x float4 = 256B contiguous per row
                const float4 wv0 = *(const float4*)(wr0 + 64*c);
                const float4 wv1 = *(const float4*)(wr1 + 64*c);
                const float4 wv2 = *(const float4*)(wr2 + 64*c);
                const float4 wv3 = *(const float4*)(wr3 + 64*c);
                #pragma unroll
                for (int d = 0; d < 4; ++d) {
                    const int kd = 4*h + 64*c + d;
                    const float* hp = smem + OFF_H + hoff(kd);
                    float4 hv0 = *(const float4*)(hp);
                    float4 hv1 = *(const float4*)(hp + 4);
                    float4 hv2 = *(const float4*)(hp + 8);
                    float4 hv3 = *(const float4*)(hp + 12);
                    const float hv[16] = {hv0.x,hv0.y,hv0.z,hv0.w, hv1.x,hv1.y,hv1.z,hv1.w,
                                          hv2.x,hv2.y,hv2.z,hv2.w, hv3.x,hv3.y,hv3.z,hv3.w};
                    const float wr4[4] = { fget(wv0,d), fget(wv1,d), fget(wv2,d), fget(wv3,d) };
                    #pragma unroll
                    for (int r = 0; r < 4; ++r)
                        #pragma unroll
                        for (int j = 0; j < 16; ++j)
                            a[r*16+j] = fmaf(wr4[r], hv[j], a[r*16+j]);
                }
            }
            RS_ROUND_L(h, 1, 32) RS_ROUND_L(h, 2, 16)
            RS_ROUND_L(h, 4, 8)  RS_ROUND_L(h, 8, 4)
            {
                const int br = ((h&1)<<3) | ((h&2)<<1) | ((h&4)>>1) | ((h&8)>>3);
                const int rr = br >> 2;
                const int jb = (br & 3) << 2;
                const int row = rr*32 + q;
                const float bv = smem[OFF_OB + row];
                float4 val = { a[0]+bv, a[1]+bv, a[2]+bv, a[3]+bv };
                *(float4*)&smem[OFF_LV + lvoff(row) + jb] = val;
            }
            __syncthreads();

            const int b2 = tid >> 5, l = tid & 31;
            float vals[4]; float m = -INFINITY; int mi = 0x7fffffff;
            #pragma unroll
            for (int r = 0; r < 4; ++r) {
                const int row = l*4 + r;
                const float x = (row < RPB) ? smem[OFF_LV + lvoff(row) + b2] : -INFINITY;
                vals[r] = x;
                if (x > m) { m = x; mi = row; }
            }
            #pragma unroll
            for (int o = 16; o >= 1; o >>= 1) {
                float om = __shfl_xor(m, o); int oi = __shfl_xor(mi, o);
                if (om > m || (om == m && oi < mi)) { m = om; mi = oi; }
            }
            float z = 0.f;
            #pragma unroll
            for (int r = 0; r < 4; ++r) z += expf(vals[r] - m);
            #pragma unroll
            for (int o = 16; o >= 1; o >>= 1) z += __shfl_xor(z, o);
            if (l == 0) {
                astore(p.pm  + blk*BB + b2, m);
                astore(p.psm + blk*BB + b2, z);
                astorei(p.pid + blk*BB + b2, gv0 + mi);
            }
        }
        if (blk < BB && i < TT) {
            const int b = blk;
            if (i == 0) smem[A_HB + tid] = p.h0i[BH + b*HH + tid];
            else        smem[A_HB + tid] = smem[OFF_H + hoff(tid) + b];
            __syncthreads();
            {   // scores[s] = dot(h1prev[b], enc[s][b]); 4 lanes per s
                const int s = tid >> 2, kq = tid & 3;
                const float* ep = p.enc + ((long)s*BB + b)*HH + kq*128;
                const float* hp = smem + A_HB + kq*128;
                float a0=0,a1=0,a2=0,a3=0;
                #pragma unroll 4
                for (int k = 0; k < 128; k += 16) {
                    float4 e0 = *(const float4*)(ep+k),    v0 = *(const float4*)(hp+k);
                    float4 e1 = *(const float4*)(ep+k+4),  v1 = *(const float4*)(hp+k+4);
                    float4 e2 = *(const float4*)(ep+k+8),  v2 = *(const float4*)(hp+k+8);
                    float4 e3 = *(const float4*)(ep+k+12), v3 = *(const float4*)(hp+k+12);
                    a0 += e0.x*v0.x+e0.y*v0.y+e0.z*v0.z+e0.w*v0.w;
                    a1 += e1.x*v1.x+e1.y*v1.y+e1.z*v1.z+e1.w*v1.w;
                    a2 += e2.x*v2.x+e2.y*v2.y+e2.z*v2.z+e2.w*v2.w;
                    a3 += e3.x*v3.x+e3.y*v3.y+e3.z*v3.z+e3.w*v3.w;
                }
                float a = (a0+a1)+(a2+a3);
                a += __shfl_xor(a, 1); a += __shfl_xor(a, 2);
                if (kq == 0) smem[A_SC + s] = a;
            }
            __syncthreads();
            float sc = (tid < SS) ? smem[A_SC + tid] : -INFINITY;
            float M2 = bredmax(sc, s8, tid);
            float e  = (tid < SS) ? expf(sc - M2) : 0.f;
            float Z2 = bredsum(e, s8, tid);
            if (tid < SS) {
                const float av = e / Z2;
                smem[A_AW + tid] = av;
                __builtin_nontemporal_store(av, p.attn + ((long)b*TT + i)*SS + tid);
            }
            __syncthreads();
            float c0=0,c1=0,c2=0,c3=0;
            const float* ep2 = p.enc + b*HH + tid;
            for (int s = 0; s < SS; s += 4) {
                c0 = fmaf(smem[A_AW+s],   ep2[(long)s*BH],     c0);
                c1 = fmaf(smem[A_AW+s+1], ep2[(long)(s+1)*BH], c1);
                c2 = fmaf(smem[A_AW+s+2], ep2[(long)(s+2)*BH], c2);
                c3 = fmaf(smem[A_AW+s+3], ep2[(long)(s+3)*BH], c3);
            }
            astore(p.xbuf + b*HH + tid, (c0+c1)+(c2+c3));
        }
        gbar(p.wsbar, ++bt);

        // ================= phase B: combine + logp(i-1) + LSTM0 ==============
        if (i >= 1) {
            const int bC = tid >> 5, lC = tid & 31;
            float pmv[8]; float psv[8]; int piv[8];
            #pragma unroll
            for (int j2 = 0; j2 < 8; ++j2) {
                const int src = (lC + 32*j2)*BB + bC;
                pmv[j2] = aload(p.pm + src);
                psv[j2] = aload(p.psm + src);
                piv[j2] = aloadi(p.pid + src);
            }
            float M = pmv[0]; int Mi = piv[0];
            #pragma unroll
            for (int j2 = 1; j2 < 8; ++j2)
                if (pmv[j2] > M || (pmv[j2] == M && piv[j2] < Mi)) { M = pmv[j2]; Mi = piv[j2]; }
            #pragma unroll
            for (int o = 16; o >= 1; o >>= 1) {
                float om = __shfl_xor(M, o); int oi = __shfl_xor(Mi, o);
                if (om > M || (om == M && oi < Mi)) { M = om; Mi = oi; }
            }
            float z = 0.f;
            #pragma unroll
            for (int j2 = 0; j2 < 8; ++j2) z += psv[j2] * expf(pmv[j2] - M);
            #pragma unroll
            for (int o = 16; o >= 1; o >>= 1) z += __shfl_xor(z, o);
            if (lC == 0) {
                ((int*)smem)[OFF_TOK + bC] = Mi;
                smem[OFF_LSEL + bC] = M + logf(z);
            }
        } else {
            if (tid < BB) ((int*)smem)[OFF_TOK + tid] = 1;
        }
        __syncthreads();

        if (i >= 1) {
            if (blk < BB && tid == 0)
                __builtin_nontemporal_store((float)((int*)smem)[OFF_TOK + blk],
                                            p.seqo + blk*TT + (i-1));
            for (int ii = tid; ii < BB*128; ii += NT) {
                const int b2 = ii >> 7, r = ii & 127;
                if (r < RPB)
                    __builtin_nontemporal_store(smem[OFF_LV + lvoff(r) + b2] - smem[OFF_LSEL + b2],
                                                p.out + ((long)b2*TT + (i-1))*VV + gv0 + r);
            }
        }
        if (i < TT) {
            const float* hold = (i == 0) ? p.h0i : p.st + (pp*2)*BH;
            float* hnew = p.st + (pc*2)*BH;
            const int g4 = tid >> 7, l = tid & 127, lane = tid & 63, wh2 = (tid >> 6) & 1;
            const float* wbA = smem + OFF_W0 + (g4*2)   * W0STR;
            const float* wbB = smem + OFF_W0 + (g4*2+1) * W0STR;
            const float4 wxaA = wat(wbA, 8*l), wxbA = wat(wbA, 8*l+4), whA = wat(wbA, 1024+4*l);
            const float4 wxaB = wat(wbB, 8*l), wxbB = wat(wbB, 8*l+4), whB = wat(wbB, 1024+4*l);
            int toks[16];
            #pragma unroll
            for (int b = 0; b < 16; ++b) toks[b] = ((int*)smem)[OFF_TOK + b];
            float a[32];
            #pragma unroll
            for (int b = 0; b < 16; ++b) {
                float x0,x1,x2,x3,x4,x5,x6,x7;
                if (l < 64) {
                    const float4 e0 = *(const float4*)(p.emb + (long)toks[b]*EE + 8*l);
                    const float4 e1 = *(const float4*)(p.emb + (long)toks[b]*EE + 8*l + 4);
                    x0=e0.x; x1=e0.y; x2=e0.z; x3=e0.w;
                    x4=e1.x; x5=e1.y; x6=e1.z; x7=e1.w;
                } else {
                    const float* cb = p.xbuf + b*HH + (8*l - 512);
                    x0=aload(cb);   x1=aload(cb+1); x2=aload(cb+2); x3=aload(cb+3);
                    x4=aload(cb+4); x5=aload(cb+5); x6=aload(cb+6); x7=aload(cb+7);
                }
                const float* hb2 = hold + b*HH + 4*l;
                const float h0v=aload(hb2), h1v=aload(hb2+1), h2v=aload(hb2+2), h3v=aload(hb2+3);
                float sA = 0.f, sB = 0.f;
                sA = fmaf(wxaA.x,x0, fmaf(wxaA.y,x1, fmaf(wxaA.z,x2, fmaf(wxaA.w,x3, sA))));
                sA = fmaf(wxbA.x,x4, fmaf(wxbA.y,x5, fmaf(wxbA.z,x6, fmaf(wxbA.w,x7, sA))));
                sA = fmaf(whA.x,h0v, fmaf(whA.y,h1v, fmaf(whA.z,h2v, fmaf(whA.w,h3v, sA))));
                sB = fmaf(wxaB.x,x0, fmaf(wxaB.y,x1, fmaf(wxaB.z,x2, fmaf(wxaB.w,x3, sB))));
                sB = fmaf(wxbB.x,x4, fmaf(wxbB.y,x5, fmaf(wxbB.z,x6, fmaf(wxbB.w,x7, sB))));
                sB = fmaf(whB.x,h0v, fmaf(whB.y,h1v, fmaf(whB.z,h2v, fmaf(whB.w,h3v, sB))));
                a[b] = sA; a[16 + b] = sB;
            }
            RS_ROUND_L(lane, 1, 16) RS_ROUND_L(lane, 2, 8)
            RS_ROUND_L(lane, 4, 4)  RS_ROUND_L(lane, 8, 2)
            RS_ROUND_L(lane, 16, 1)
            float v = a[0]; v += __shfl_xor(v, 32);
            const int lg = lane & 31;
            const int g = ((lg&1)<<4)|((lg&2)<<2)|(lg&4)|((lg&8)>>2)|((lg&16)>>4);
            if (lane < 32) smem[A_GP + (g4*2 + wh2)*32 + g] = v;
            __syncthreads();
            if (tid < 32) {
                const int b = tid >> 1, jj = tid & 1, gg2 = jj*16 + b;
                const float gi = smem[A_GP + 0*32+gg2] + smem[A_GP + 1*32+gg2] + smem[OFF_BS + 0 + jj];
                const float gf = smem[A_GP + 2*32+gg2] + smem[A_GP + 3*32+gg2] + smem[OFF_BS + 2 + jj];
                const float gc = smem[A_GP + 4*32+gg2] + smem[A_GP + 5*32+gg2] + smem[OFF_BS + 4 + jj];
                const float go = smem[A_GP + 6*32+gg2] + smem[A_GP + 7*32+gg2] + smem[OFF_BS + 6 + jj];
                const float cp = smem[OFF_CST + jj*16 + b];
                const float cn = sigf(gf)*cp + sigf(gi)*tanhf(gc);
                const float hn = sigf(go)*tanhf(cn);
                smem[OFF_CST + jj*16 + b] = cn;
                astore(hnew + b*HH + j0 + jj, hn);
            }
        }
        if (i == TT) break;
        gbar(p.wsbar, ++bt);

        // ================= phase C: LSTM1 =================
        {
            const float* xsrc = p.st + (pc*2)*BH;                       // h0[i]
            const float* hold = (i == 0) ? p.h0i + BH : p.st + (pp*2 + 1)*BH;
            float* hnew = p.st + (pc*2 + 1)*BH;
            const int g4 = tid >> 7, l = tid & 127, lane = tid & 63, wh2 = (tid >> 6) & 1;
            const float* wbA = smem + OFF_W1 + (g4*2)   * W1STR;
            const float* wbB = smem + OFF_W1 + (g4*2+1) * W1STR;
            const float4 wxA = wat(wbA, 4*l), whA = wat(wbA, 512+4*l);
            const float4 wxB = wat(wbB, 4*l), whB = wat(wbB, 512+4*l);
            float a[32];
            #pragma unroll
            for (int b = 0; b < 16; ++b) {
                const float* xb2 = xsrc + b*HH + 4*l;
                const float* hb2 = hold + b*HH + 4*l;
                const float x0=aload(xb2), x1=aload(xb2+1), x2=aload(xb2+2), x3=aload(xb2+3);
                const float h0v=aload(hb2), h1v=aload(hb2+1), h2v=aload(hb2+2), h3v=aload(hb2+3);
                float sA = 0.f, sB = 0.f;
                sA = fmaf(wxA.x,x0, fmaf(wxA.y,x1, fmaf(wxA.z,x2, fmaf(wxA.w,x3, sA))));
                sA = fmaf(whA.x,h0v, fmaf(whA.y,h1v, fmaf(whA.z,h2v, fmaf(whA.w,h3v, sA))));
                sB = fmaf(wxB.x,x0, fmaf(wxB.y,x1, fmaf(wxB.z,x2, fmaf(wxB.w,x3, sB))));
                sB = fmaf(whB.x,h0v, fmaf(whB.y,h1v, fmaf(whB.z,h2v, fmaf(whB.w,h3v, sB))));
                a[b] = sA; a[16 + b] = sB;
            }
            RS_ROUND_L(lane, 1, 16) RS_ROUND_L(lane, 2, 8)
            RS_ROUND_L(lane, 4, 4)  RS_ROUND_L(lane, 8, 2)
            RS_ROUND_L(lane, 16, 1)
            float v = a[0]; v += __shfl_xor(v, 32);
            const int lg = lane & 31;
            const int g = ((lg&1)<<4)|((lg&2)<<2)|(lg&4)|((lg&8)>>2)|((lg&16)>>4);
            if (lane < 32) smem[A_GP + (g4*2 + wh2)*32 + g] = v;
            __syncthreads();
            if (tid < 32) {
                const int b = tid >> 1, jj = tid & 1, gg2 = jj*16 + b;
                const float gi = smem[A_GP + 0*32+gg2] + smem[A_GP + 1*32+gg2] + smem[OFF_BS + 8 + 0 + jj];
                const float gf = smem[A_GP + 2*32+gg2] + smem[A_GP + 3*32+gg2] + smem[OFF_BS + 8 + 2 + jj];
                const float gc = smem[A_GP + 4*32+gg2] + smem[A_GP + 5*32+gg2] + smem[OFF_BS + 8 + 4 + jj];
                const float go = smem[A_GP + 6*32+gg2] + smem[A_GP + 7*32+gg2] + smem[OFF_BS + 8 + 6 + jj];
                const float cp = smem[OFF_CST + 32 + jj*16 + b];
                const float cn = sigf(gf)*cp + sigf(gi)*tanhf(gc);
                const float hn = sigf(go)*tanhf(cn);
                smem[OFF_CST + 32 + jj*16 + b] = cn;
                astore(hnew + b*HH + j0 + jj, hn);
            }
        }
        gbar(p.wsbar, ++bt);
    }
}

extern "C" void kernel_launch(void* const* d_in, const int* in_sizes, int n_in,
                              void* d_out, int out_size, void* d_ws, size_t ws_size,
                              hipStream_t stream)
{
    (void)in_sizes; (void)n_in; (void)out_size; (void)ws_size;
    Params p;
    p.emb  = (const float*)d_in[0];
    p.h0i  = (const float*)d_in[1];
    p.c0i  = (const float*)d_in[2];
    p.enc  = (const float*)d_in[3];
    p.wih0 = (const float*)d_in[4];
    p.whh0 = (const float*)d_in[5];
    p.bih0 = (const float*)d_in[6];
    p.bhh0 = (const float*)d_in[7];
    p.wih1 = (const float*)d_in[8];
    p.whh1 = (const float*)d_in[9];
    p.bih1 = (const float*)d_in[10];
    p.bhh1 = (const float*)d_in[11];
    p.ow   = (const float*)d_in[12];
    p.ob   = (const float*)d_in[13];

    float* out = (float*)d_out;
    p.out  = out;
    p.seqo = out + (long)BB*TT*VV;
    p.attn = p.seqo + (long)BB*TT;

    p.wsbar = (int*)d_ws;                      // 1024 ints (4 KB), zeroed below
    float* base = (float*)d_ws + 1024;
    p.st    = base;                            // 2 parity x {h0,h1} x B*H = 32768
    p.xbuf  = p.st + 4*BH;                     // ctx: B x H = 8192
    p.pm    = p.xbuf + BH;                     // NB x B = 4096
    p.psm   = p.pm + NB*BB;                    // 4096
    p.pid   = (int*)(p.psm + NB*BB);           // 4096

    hipMemsetAsync(d_ws, 0, 4096, stream);     // reset barrier state every launch
    void* args[] = { &p };
    hipLaunchCooperativeKernel((void*)k_decode, dim3(NB), dim3(NT), args, 0, stream);
}